// Round 1
// 239.010 us; speedup vs baseline: 1.2938x; 1.2938x over previous
//
#include <hip/hip_runtime.h>
#include <math.h>

// Problem constants (match reference)
#define BB 256
#define WD 19
#define HD 19
#define AD 5
#define CD 80
#define TD 20
#define N1 462080                 // B*W*H*A
#define NCLS (N1 * CD)            // 36,966,400 floats (147.9 MB)
#define NPRED (N1 * 5)            // 2,310,400 floats (9.2 MB)

#define NC4 (NCLS / 4)            // 9,241,600 float4
#define NP4 (NPRED / 4)           // 577,600 float4

// batches of 1024 float4 (16 KB), one wave covers a batch as 16 x 64 lanes
#define CLS_BATCHES (NC4 / 1024)   // 9,025 exact (no tail)
#define PRED_BATCHES (NP4 / 1024)  // 564 full, tail 64 float4

// grid: [0,100) corrections | [100,996) cls | [996,1060) pred
#define NB_CORR 100
#define NB_CLS  896
#define NB_PRED 64
#define NBLK (NB_CORR + NB_CLS + NB_PRED)   // 1060
#define CLS_WAVES (NB_CLS * 4)    // 3584 -> ~2.5 batches/wave
#define PRED_WAVES (NB_PRED * 4)  // 256  -> ~2.2 batches/wave

typedef float f32x4 __attribute__((ext_vector_type(4)));

#define GLOAD(dst, voff, base, imm)                                   \
    asm volatile("global_load_dwordx4 %0, %1, %2 offset:" imm         \
                 : "=v"(dst) : "v"(voff), "s"(base))

__device__ __forceinline__ float sigmoidf_(float x) {
    return 1.0f / (1.0f + expf(-x));
}

// Load batch b (1024 float4, 16 KB) with 16 loads in flight, then full drain.
#define LOAD_BATCH16(src, b, lane)                                    \
    unsigned o0 = (unsigned)((b) * 1024 + (lane)) * 16u;              \
    unsigned o1 = o0 + 4096u;                                         \
    unsigned o2 = o0 + 8192u;                                         \
    unsigned o3 = o0 + 12288u;                                        \
    f32x4 v0, v1, v2, v3, v4, v5, v6, v7;                             \
    f32x4 v8, v9, v10, v11, v12, v13, v14, v15;                       \
    GLOAD(v0,  o0, src, "0");                                         \
    GLOAD(v1,  o0, src, "1024");                                      \
    GLOAD(v2,  o0, src, "2048");                                      \
    GLOAD(v3,  o0, src, "3072");                                      \
    GLOAD(v4,  o1, src, "0");                                         \
    GLOAD(v5,  o1, src, "1024");                                      \
    GLOAD(v6,  o1, src, "2048");                                      \
    GLOAD(v7,  o1, src, "3072");                                      \
    GLOAD(v8,  o2, src, "0");                                         \
    GLOAD(v9,  o2, src, "1024");                                      \
    GLOAD(v10, o2, src, "2048");                                      \
    GLOAD(v11, o2, src, "3072");                                      \
    GLOAD(v12, o3, src, "0");                                         \
    GLOAD(v13, o3, src, "1024");                                      \
    GLOAD(v14, o3, src, "2048");                                      \
    GLOAD(v15, o3, src, "3072");                                      \
    asm volatile("s_waitcnt vmcnt(0)"                                 \
                 : "+v"(v0), "+v"(v1), "+v"(v2),  "+v"(v3),           \
                   "+v"(v4), "+v"(v5), "+v"(v6),  "+v"(v7),           \
                   "+v"(v8), "+v"(v9), "+v"(v10), "+v"(v11),          \
                   "+v"(v12), "+v"(v13), "+v"(v14), "+v"(v15));

// Wave-reduce 8 values, lane 0 of each wave deposits to LDS.
// NO global atomics anywhere: each block owns ws[bx*8 .. bx*8+7] (64 B line).
// Previous version fired ~9.4K device-scope f64 atomics at ONE cache line
// (~15 ns each serialized = the whole 139 us kernel duration).
__device__ __forceinline__ void commit_wave(double (*sred)[8], int wib, int lane,
                                            float a0, float a1, float a2, float a3,
                                            float a4, float a5, float a6, float a7) {
    float v[8] = {a0, a1, a2, a3, a4, a5, a6, a7};
    #pragma unroll
    for (int s = 0; s < 8; ++s) {
        #pragma unroll
        for (int off = 32; off > 0; off >>= 1)
            v[s] += __shfl_down(v[s], off, 64);
    }
    if (lane == 0) {
        #pragma unroll
        for (int s = 0; s < 8; ++s) sred[wib][s] = (double)v[s];
    }
}

// ws layout (doubles): ws[bx*8 + s], bx in [0,1060), slots:
// 0 sum(cls^2) | 1 sum(cls[...,79]) | 2 sum(conf^2) | 3 noobj_rm
// 4 obj | 5 prior | 6 true | 7 score corr      (total 67,840 B workspace)
__global__ void __launch_bounds__(256)
yolo_fused(const float* __restrict__ cls,
           const float* __restrict__ pred,
           const float* __restrict__ tobj,
           const float* __restrict__ tlab,
           const float* __restrict__ anchors,
           const float* __restrict__ fm_cord,
           const float* __restrict__ fm_size,
           double* __restrict__ ws) {
    const int bx = blockIdx.x;
    const int lane = threadIdx.x & 63;
    const int wib = threadIdx.x >> 6;

    __shared__ double sred[4][8];

    if (bx >= NB_CORR && bx < NB_CORR + NB_CLS) {
        // ---------------- cls: sum(cls^2), sum(cls[...,79]) ----------------
        const int wave = (bx - NB_CORR) * 4 + wib;
        const int b0 = (int)(((long long)wave * CLS_BATCHES) / CLS_WAVES);
        const int b1 = (int)(((long long)(wave + 1) * CLS_BATCHES) / CLS_WAVES);

        float sumsq = 0.0f, sum79 = 0.0f;

        for (int b = b0; b < b1; ++b) {
            LOAD_BATCH16(cls, b, lane);
            // gi = b*1024 + k*64 + lane ; gi%20 = (base20 + 4k) % 20
            const int base20 = (b * 1024 + lane) % 20;
            const f32x4 vv[16] = {v0, v1, v2, v3, v4, v5, v6, v7,
                                  v8, v9, v10, v11, v12, v13, v14, v15};
            #pragma unroll
            for (int k = 0; k < 16; ++k) {
                f32x4 v = vv[k];
                sumsq += v.x * v.x + v.y * v.y + v.z * v.z + v.w * v.w;
                int t = base20 + 4 * k;           // <= 79
                if (t == 19 || t == 39 || t == 59 || t == 79) sum79 += v.w;
            }
        }

        commit_wave(sred, wib, lane, sumsq, sum79, 0.f, 0.f, 0.f, 0.f, 0.f, 0.f);
    } else if (bx >= NB_CORR + NB_CLS) {
        // ---------------- pred: sum(sigmoid(conf)^2) ----------------
        const int wave = (bx - NB_CORR - NB_CLS) * 4 + wib;
        const int b0 = (int)(((long long)wave * PRED_BATCHES) / PRED_WAVES);
        const int b1 = (int)(((long long)(wave + 1) * PRED_BATCHES) / PRED_WAVES);

        float conf2 = 0.0f;

        for (int b = b0; b < b1; ++b) {
            LOAD_BATCH16(pred, b, lane);
            // gi%5 ; conf component kk = (gi+4)%5 if <4
            const int base5 = (b * 1024 + lane) % 5;
            const f32x4 vv[16] = {v0, v1, v2, v3, v4, v5, v6, v7,
                                  v8, v9, v10, v11, v12, v13, v14, v15};
            #pragma unroll
            for (int k = 0; k < 16; ++k) {
                f32x4 v = vv[k];
                int g5 = (base5 + 4 * k) % 5;
                int kk = (g5 + 4) % 5;            // 4 => no conf element here
                if (kk < 4) {
                    float x = (kk == 0) ? v.x : (kk == 1) ? v.y
                            : (kk == 2) ? v.z : v.w;
                    float c = sigmoidf_(x);
                    conf2 += c * c;
                }
            }
        }

        // tail: 64 float4 (gi = 577536 + lane), last wave only
        if (wave == PRED_WAVES - 1) {
            int gi = PRED_BATCHES * 1024 + lane;
            float4 v = reinterpret_cast<const float4*>(pred)[gi];
            int kk = (gi + 4) % 5;
            if (kk < 4) {
                float x = (kk == 0) ? v.x : (kk == 1) ? v.y : (kk == 2) ? v.z : v.w;
                float c = sigmoidf_(x);
                conf2 += c * c;
            }
        }

        commit_wave(sred, wib, lane, 0.f, 0.f, conf2, 0.f, 0.f, 0.f, 0.f, 0.f);
    } else {
        // ---------------- sparse corrections (blocks 0..99) ----------------
        const int id = bx * 256 + threadIdx.x;
        float noobj_rm = 0.0f, objs = 0.0f, priors = 0.0f, trues = 0.0f, scorr = 0.0f;

        if (id < BB * TD * AD) {
            int b = id / (TD * AD);
            int r = id % (TD * AD);
            int t = r / AD;
            int a = r % AD;

            const float4 to4 = reinterpret_cast<const float4*>(tobj)[b * TD + t];
            float tox = to4.x * (1.0f / 32.0f);
            float toy = to4.y * (1.0f / 32.0f);
            float tw  = to4.z * (1.0f / 32.0f);
            float th  = to4.w * (1.0f / 32.0f);
            int ii = (int)floorf(tox);
            int jj = (int)floorf(toy);

            const int cell = (b * WD + ii) * HD + jj;
            const float* p = pred + (cell * AD + a) * 5;
            const int fm = (ii * HD + jj) * 2;
            float px = sigmoidf_(p[0]) + fm_cord[fm + 0];
            float py = sigmoidf_(p[1]) + fm_cord[fm + 1];
            float pw = sigmoidf_(p[2]) * fm_size[fm + 0];
            float ph = sigmoidf_(p[3]) * fm_size[fm + 1];
            float conf = sigmoidf_(p[4]);

            float inter = fminf(pw, tw) * fminf(ph, th);
            float uni = pw * ph + tw * th - inter;
            float iou = inter / uni;

            if (iou > 0.5f) {
                noobj_rm = conf * conf;
                objs = (conf - iou) * (conf - iou);
                float aw = anchors[a * 2 + 0];
                float ah = anchors[a * 2 + 1];
                priors = (pw - aw) * (pw - aw) + (ph - ah) * (ph - ah);
                trues = (px - tox) * (px - tox) + (py - toy) * (py - toy)
                      + (pw - tw) * (pw - tw) + (ph - th) * (ph - th);
                // score replacement: sum(cls-tl)^2 - sum(cls-onehot79)^2
                //                  = 2*cls[79] - 2*dot(cls, tl)   (tl one-hot)
                const float4* cl4 = reinterpret_cast<const float4*>(cls + (cell * AD + a) * CD);
                const float4* tl4 = reinterpret_cast<const float4*>(tlab + (b * TD + t) * CD);
                float dot = 0.0f;
                float cl79 = 0.0f;
                #pragma unroll 5
                for (int c = 0; c < CD / 4; ++c) {
                    float4 x = cl4[c];
                    float4 y = tl4[c];
                    dot += x.x * y.x + x.y * y.y + x.z * y.z + x.w * y.w;
                    if (c == CD / 4 - 1) cl79 = x.w;
                }
                scorr = 2.0f * cl79 - 2.0f * dot;
            }
        }

        commit_wave(sred, wib, lane, 0.f, 0.f, 0.f, noobj_rm, objs, priors, trues, scorr);
    }

    __syncthreads();
    if (threadIdx.x < 8) {
        ws[bx * 8 + threadIdx.x] = sred[0][threadIdx.x] + sred[1][threadIdx.x]
                                 + sred[2][threadIdx.x] + sred[3][threadIdx.x];
    }
}

__global__ void __launch_bounds__(256)
yolo_finalize(const double* __restrict__ ws,
              const int* __restrict__ epoch_p,
              float* __restrict__ out) {
    const int lane = threadIdx.x & 63;
    const int wib = threadIdx.x >> 6;
    __shared__ double sh[4][8];

    double acc[8] = {0.0, 0.0, 0.0, 0.0, 0.0, 0.0, 0.0, 0.0};
    for (int b = threadIdx.x; b < NBLK; b += 256) {
        #pragma unroll
        for (int s = 0; s < 8; ++s) acc[s] += ws[b * 8 + s];
    }
    #pragma unroll
    for (int s = 0; s < 8; ++s) {
        #pragma unroll
        for (int off = 32; off > 0; off >>= 1)
            acc[s] += __shfl_down(acc[s], off, 64);
    }
    if (lane == 0) {
        #pragma unroll
        for (int s = 0; s < 8; ++s) sh[wib][s] = acc[s];
    }
    __syncthreads();

    if (threadIdx.x == 0) {
        double v[8];
        #pragma unroll
        for (int s = 0; s < 8; ++s)
            v[s] = sh[0][s] + sh[1][s] + sh[2][s] + sh[3][s];

        const double n1 = (double)N1;
        double sumsq = v[0], sum79 = v[1], conf2 = v[2];
        double rm = v[3], objs = v[4], priors = v[5], trues = v[6], scorr = v[7];

        int ev = epoch_p[0];
        double epoch;
        if (ev >= 0 && ev <= 1000000) {
            epoch = (double)ev;
        } else {
            float f = __int_as_float(ev);
            epoch = (double)f;
        }
        double need_prior = (epoch < 10.0) ? 1.0 : 0.0;

        double noobj_loss = 0.25 * (conf2 - rm) / n1;
        double obj_loss   = 2.5 * objs / n1;
        double prior_loss = need_prior * 2.5 * priors / (2.0 * n1);
        double true_loss  = 2.5 * trues / (4.0 * n1);
        double score_base = sumsq + n1 - 2.0 * sum79;
        double score_loss = 2.5 * (score_base + scorr) / (80.0 * n1);

        out[0] = (float)((noobj_loss + obj_loss + prior_loss + true_loss + score_loss) / 4.0);
    }
}

extern "C" void kernel_launch(void* const* d_in, const int* in_sizes, int n_in,
                              void* d_out, int out_size, void* d_ws, size_t ws_size,
                              hipStream_t stream) {
    const int*   epoch   = (const int*)d_in[0];
    const float* cls     = (const float*)d_in[1];
    const float* pred    = (const float*)d_in[2];
    const float* tobj    = (const float*)d_in[3];
    const float* tlab    = (const float*)d_in[4];
    const float* anchors = (const float*)d_in[5];
    const float* fm_cord = (const float*)d_in[6];
    const float* fm_size = (const float*)d_in[7];
    double* ws = (double*)d_ws;
    float* out = (float*)d_out;

    // No memset needed: every block writes all 8 of its private ws slots.
    yolo_fused<<<NBLK, 256, 0, stream>>>(
        cls, pred, tobj, tlab, anchors, fm_cord, fm_size, ws);

    yolo_finalize<<<1, 256, 0, stream>>>(ws, epoch, out);
}

// Round 2
// 238.330 us; speedup vs baseline: 1.2975x; 1.0029x over previous
//
#include <hip/hip_runtime.h>
#include <math.h>

// Problem constants (match reference)
#define BB 256
#define WD 19
#define HD 19
#define AD 5
#define CD 80
#define TD 20
#define N1 462080                 // B*W*H*A
#define NCLS (N1 * CD)            // 36,966,400 floats (147.9 MB)
#define NPRED (N1 * 5)            // 2,310,400 floats (9.2 MB)

#define NC4 (NCLS / 4)            // 9,241,600 float4
#define NP4 (NPRED / 4)           // 577,600 float4

// batches of 1024 float4 (16 KB), one wave covers a batch as 16 x 64 lanes.
// ONE batch per wave now: max TLP, single load-burst + single drain per wave.
#define CLS_BATCHES (NC4 / 1024)   // 9,025 exact (no tail)
#define PRED_BATCHES (NP4 / 1024)  // 564 full, tail 64 float4

// grid: [0,100) corrections | [100, 100+2257) cls | [...,+141) pred
#define NB_CORR 100
#define NB_CLS  2257               // ceil(9025/4) waves -> 1 batch each
#define NB_PRED 141                // 564/4 waves -> 1 batch each
#define NBLK (NB_CORR + NB_CLS + NB_PRED)   // 2498

typedef float f32x4 __attribute__((ext_vector_type(4)));

#define GLOAD(dst, voff, base, imm)                                   \
    asm volatile("global_load_dwordx4 %0, %1, %2 offset:" imm         \
                 : "=v"(dst) : "v"(voff), "s"(base))

__device__ __forceinline__ float sigmoidf_(float x) {
    return 1.0f / (1.0f + expf(-x));
}

// Load batch b (1024 float4, 16 KB) with 16 loads in flight, then full drain.
#define LOAD_BATCH16(src, b, lane)                                    \
    unsigned o0 = (unsigned)((b) * 1024 + (lane)) * 16u;              \
    unsigned o1 = o0 + 4096u;                                         \
    unsigned o2 = o0 + 8192u;                                         \
    unsigned o3 = o0 + 12288u;                                        \
    f32x4 v0, v1, v2, v3, v4, v5, v6, v7;                             \
    f32x4 v8, v9, v10, v11, v12, v13, v14, v15;                       \
    GLOAD(v0,  o0, src, "0");                                         \
    GLOAD(v1,  o0, src, "1024");                                      \
    GLOAD(v2,  o0, src, "2048");                                      \
    GLOAD(v3,  o0, src, "3072");                                      \
    GLOAD(v4,  o1, src, "0");                                         \
    GLOAD(v5,  o1, src, "1024");                                      \
    GLOAD(v6,  o1, src, "2048");                                      \
    GLOAD(v7,  o1, src, "3072");                                      \
    GLOAD(v8,  o2, src, "0");                                         \
    GLOAD(v9,  o2, src, "1024");                                      \
    GLOAD(v10, o2, src, "2048");                                      \
    GLOAD(v11, o2, src, "3072");                                      \
    GLOAD(v12, o3, src, "0");                                         \
    GLOAD(v13, o3, src, "1024");                                      \
    GLOAD(v14, o3, src, "2048");                                      \
    GLOAD(v15, o3, src, "3072");                                      \
    asm volatile("s_waitcnt vmcnt(0)"                                 \
                 : "+v"(v0), "+v"(v1), "+v"(v2),  "+v"(v3),           \
                   "+v"(v4), "+v"(v5), "+v"(v6),  "+v"(v7),           \
                   "+v"(v8), "+v"(v9), "+v"(v10), "+v"(v11),          \
                   "+v"(v12), "+v"(v13), "+v"(v14), "+v"(v15));

// Wave-reduce 8 values, lane 0 of each wave deposits to LDS.
// NO global atomics anywhere: each block owns ws[bx*8 .. bx*8+7] (64 B line).
__device__ __forceinline__ void commit_wave(double (*sred)[8], int wib, int lane,
                                            float a0, float a1, float a2, float a3,
                                            float a4, float a5, float a6, float a7) {
    float v[8] = {a0, a1, a2, a3, a4, a5, a6, a7};
    #pragma unroll
    for (int s = 0; s < 8; ++s) {
        #pragma unroll
        for (int off = 32; off > 0; off >>= 1)
            v[s] += __shfl_down(v[s], off, 64);
    }
    if (lane == 0) {
        #pragma unroll
        for (int s = 0; s < 8; ++s) sred[wib][s] = (double)v[s];
    }
}

// ws layout (doubles): ws[bx*8 + s], bx in [0,2498), slots:
// 0 sum(cls^2) | 1 sum(cls[...,79]) | 2 sum(conf^2) | 3 noobj_rm
// 4 obj | 5 prior | 6 true | 7 score corr      (total 159,872 B workspace)
__global__ void __launch_bounds__(256)
yolo_fused(const float* __restrict__ cls,
           const float* __restrict__ pred,
           const float* __restrict__ tobj,
           const float* __restrict__ tlab,
           const float* __restrict__ anchors,
           const float* __restrict__ fm_cord,
           const float* __restrict__ fm_size,
           double* __restrict__ ws) {
    const int bx = blockIdx.x;
    const int lane = threadIdx.x & 63;
    const int wib = threadIdx.x >> 6;

    __shared__ double sred[4][8];

    if (bx >= NB_CORR && bx < NB_CORR + NB_CLS) {
        // ---------------- cls: sum(cls^2), sum(cls[...,79]) ----------------
        const int wave = (bx - NB_CORR) * 4 + wib;   // [0, 9028); batch = wave
        float sumsq = 0.0f, sum79 = 0.0f;

        if (wave < CLS_BATCHES) {
            const int b = wave;
            LOAD_BATCH16(cls, b, lane);
            // gi = b*1024 + k*64 + lane ; gi%20 = (base20 + 4k) % 20
            const int base20 = (b * 1024 + lane) % 20;
            const f32x4 vv[16] = {v0, v1, v2, v3, v4, v5, v6, v7,
                                  v8, v9, v10, v11, v12, v13, v14, v15};
            #pragma unroll
            for (int k = 0; k < 16; ++k) {
                f32x4 v = vv[k];
                sumsq += v.x * v.x + v.y * v.y + v.z * v.z + v.w * v.w;
                int t = base20 + 4 * k;           // <= 79
                if (t == 19 || t == 39 || t == 59 || t == 79) sum79 += v.w;
            }
        }

        commit_wave(sred, wib, lane, sumsq, sum79, 0.f, 0.f, 0.f, 0.f, 0.f, 0.f);
    } else if (bx >= NB_CORR + NB_CLS) {
        // ---------------- pred: sum(sigmoid(conf)^2) ----------------
        const int wave = (bx - NB_CORR - NB_CLS) * 4 + wib;  // [0, 564); batch = wave
        float conf2 = 0.0f;

        {
            const int b = wave;
            LOAD_BATCH16(pred, b, lane);
            // gi%5 ; conf component kk = (gi+4)%5 if <4
            const int base5 = (b * 1024 + lane) % 5;
            const f32x4 vv[16] = {v0, v1, v2, v3, v4, v5, v6, v7,
                                  v8, v9, v10, v11, v12, v13, v14, v15};
            #pragma unroll
            for (int k = 0; k < 16; ++k) {
                f32x4 v = vv[k];
                int g5 = (base5 + 4 * k) % 5;
                int kk = (g5 + 4) % 5;            // 4 => no conf element here
                if (kk < 4) {
                    float x = (kk == 0) ? v.x : (kk == 1) ? v.y
                            : (kk == 2) ? v.z : v.w;
                    float c = sigmoidf_(x);
                    conf2 += c * c;
                }
            }
        }

        // tail: 64 float4 (gi = 577536 + lane), last wave only
        if (wave == PRED_BATCHES - 1) {
            int gi = PRED_BATCHES * 1024 + lane;
            float4 v = reinterpret_cast<const float4*>(pred)[gi];
            int kk = (gi + 4) % 5;
            if (kk < 4) {
                float x = (kk == 0) ? v.x : (kk == 1) ? v.y : (kk == 2) ? v.z : v.w;
                float c = sigmoidf_(x);
                conf2 += c * c;
            }
        }

        commit_wave(sred, wib, lane, 0.f, 0.f, conf2, 0.f, 0.f, 0.f, 0.f, 0.f);
    } else {
        // ---------------- sparse corrections (blocks 0..99) ----------------
        const int id = bx * 256 + threadIdx.x;
        float noobj_rm = 0.0f, objs = 0.0f, priors = 0.0f, trues = 0.0f, scorr = 0.0f;

        if (id < BB * TD * AD) {
            int b = id / (TD * AD);
            int r = id % (TD * AD);
            int t = r / AD;
            int a = r % AD;

            const float4 to4 = reinterpret_cast<const float4*>(tobj)[b * TD + t];
            float tox = to4.x * (1.0f / 32.0f);
            float toy = to4.y * (1.0f / 32.0f);
            float tw  = to4.z * (1.0f / 32.0f);
            float th  = to4.w * (1.0f / 32.0f);
            int ii = (int)floorf(tox);
            int jj = (int)floorf(toy);

            const int cell = (b * WD + ii) * HD + jj;
            const float* p = pred + (cell * AD + a) * 5;
            const int fm = (ii * HD + jj) * 2;
            float px = sigmoidf_(p[0]) + fm_cord[fm + 0];
            float py = sigmoidf_(p[1]) + fm_cord[fm + 1];
            float pw = sigmoidf_(p[2]) * fm_size[fm + 0];
            float ph = sigmoidf_(p[3]) * fm_size[fm + 1];
            float conf = sigmoidf_(p[4]);

            float inter = fminf(pw, tw) * fminf(ph, th);
            float uni = pw * ph + tw * th - inter;
            float iou = inter / uni;

            if (iou > 0.5f) {
                noobj_rm = conf * conf;
                objs = (conf - iou) * (conf - iou);
                float aw = anchors[a * 2 + 0];
                float ah = anchors[a * 2 + 1];
                priors = (pw - aw) * (pw - aw) + (ph - ah) * (ph - ah);
                trues = (px - tox) * (px - tox) + (py - toy) * (py - toy)
                      + (pw - tw) * (pw - tw) + (ph - th) * (ph - th);
                // score replacement: sum(cls-tl)^2 - sum(cls-onehot79)^2
                //                  = 2*cls[79] - 2*dot(cls, tl)   (tl one-hot)
                const float4* cl4 = reinterpret_cast<const float4*>(cls + (cell * AD + a) * CD);
                const float4* tl4 = reinterpret_cast<const float4*>(tlab + (b * TD + t) * CD);
                float dot = 0.0f;
                float cl79 = 0.0f;
                #pragma unroll 5
                for (int c = 0; c < CD / 4; ++c) {
                    float4 x = cl4[c];
                    float4 y = tl4[c];
                    dot += x.x * y.x + x.y * y.y + x.z * y.z + x.w * y.w;
                    if (c == CD / 4 - 1) cl79 = x.w;
                }
                scorr = 2.0f * cl79 - 2.0f * dot;
            }
        }

        commit_wave(sred, wib, lane, 0.f, 0.f, 0.f, noobj_rm, objs, priors, trues, scorr);
    }

    __syncthreads();
    if (threadIdx.x < 8) {
        ws[bx * 8 + threadIdx.x] = sred[0][threadIdx.x] + sred[1][threadIdx.x]
                                 + sred[2][threadIdx.x] + sred[3][threadIdx.x];
    }
}

__global__ void __launch_bounds__(1024)
yolo_finalize(const double* __restrict__ ws,
              const int* __restrict__ epoch_p,
              float* __restrict__ out) {
    const int lane = threadIdx.x & 63;
    const int wib = threadIdx.x >> 6;          // 0..15
    __shared__ double sh[16][8];

    double acc[8] = {0.0, 0.0, 0.0, 0.0, 0.0, 0.0, 0.0, 0.0};
    for (int b = threadIdx.x; b < NBLK; b += 1024) {
        #pragma unroll
        for (int s = 0; s < 8; ++s) acc[s] += ws[b * 8 + s];
    }
    #pragma unroll
    for (int s = 0; s < 8; ++s) {
        #pragma unroll
        for (int off = 32; off > 0; off >>= 1)
            acc[s] += __shfl_down(acc[s], off, 64);
    }
    if (lane == 0) {
        #pragma unroll
        for (int s = 0; s < 8; ++s) sh[wib][s] = acc[s];
    }
    __syncthreads();

    if (threadIdx.x == 0) {
        double v[8];
        #pragma unroll
        for (int s = 0; s < 8; ++s) {
            double t = 0.0;
            #pragma unroll
            for (int w = 0; w < 16; ++w) t += sh[w][s];
            v[s] = t;
        }

        const double n1 = (double)N1;
        double sumsq = v[0], sum79 = v[1], conf2 = v[2];
        double rm = v[3], objs = v[4], priors = v[5], trues = v[6], scorr = v[7];

        int ev = epoch_p[0];
        double epoch;
        if (ev >= 0 && ev <= 1000000) {
            epoch = (double)ev;
        } else {
            float f = __int_as_float(ev);
            epoch = (double)f;
        }
        double need_prior = (epoch < 10.0) ? 1.0 : 0.0;

        double noobj_loss = 0.25 * (conf2 - rm) / n1;
        double obj_loss   = 2.5 * objs / n1;
        double prior_loss = need_prior * 2.5 * priors / (2.0 * n1);
        double true_loss  = 2.5 * trues / (4.0 * n1);
        double score_base = sumsq + n1 - 2.0 * sum79;
        double score_loss = 2.5 * (score_base + scorr) / (80.0 * n1);

        out[0] = (float)((noobj_loss + obj_loss + prior_loss + true_loss + score_loss) / 4.0);
    }
}

extern "C" void kernel_launch(void* const* d_in, const int* in_sizes, int n_in,
                              void* d_out, int out_size, void* d_ws, size_t ws_size,
                              hipStream_t stream) {
    const int*   epoch   = (const int*)d_in[0];
    const float* cls     = (const float*)d_in[1];
    const float* pred    = (const float*)d_in[2];
    const float* tobj    = (const float*)d_in[3];
    const float* tlab    = (const float*)d_in[4];
    const float* anchors = (const float*)d_in[5];
    const float* fm_cord = (const float*)d_in[6];
    const float* fm_size = (const float*)d_in[7];
    double* ws = (double*)d_ws;
    float* out = (float*)d_out;

    // No memset needed: every block writes all 8 of its private ws slots.
    yolo_fused<<<NBLK, 256, 0, stream>>>(
        cls, pred, tobj, tlab, anchors, fm_cord, fm_size, ws);

    yolo_finalize<<<1, 1024, 0, stream>>>(ws, epoch, out);
}

// Round 4
// 226.029 us; speedup vs baseline: 1.3681x; 1.0544x over previous
//
#include <hip/hip_runtime.h>
#include <math.h>

// Problem constants (match reference)
#define BB 256
#define WD 19
#define HD 19
#define AD 5
#define CD 80
#define TD 20
#define N1 462080                 // B*W*H*A
#define NCLS (N1 * CD)            // 36,966,400 floats (147.9 MB)
#define NPRED (N1 * 5)            // 2,310,400 floats (9.2 MB)

#define NC4 (NCLS / 4)            // 9,241,600 float4
#define NP4 (NPRED / 4)           // 577,600 float4

// batches of 1024 float4 (16 KB), one wave covers a batch as 16 x 64 lanes.
// ONE batch per wave: single load-burst + drain per wave (proven structure).
// Loads are NON-TEMPORAL: the harness poison-fill (591 MB) leaves L3 full of
// dirty lines; allocating reads force ~157 MB of writebacks during our kernel
// (~2x traffic). nt loads bypass cache allocation -> pure read stream.
#define CLS_BATCHES (NC4 / 1024)   // 9,025 exact (no tail)
#define PRED_BATCHES (NP4 / 1024)  // 564 full, tail 64 float4

// grid: [0,100) corrections | [100, 100+2257) cls | [...,+141) pred
#define NB_CORR 100
#define NB_CLS  2257               // ceil(9025/4) waves -> 1 batch each
#define NB_PRED 141                // 564/4 waves -> 1 batch each
#define NBLK (NB_CORR + NB_CLS + NB_PRED)   // 2498

typedef float f32x4 __attribute__((ext_vector_type(4)));

__device__ __forceinline__ float sigmoidf_(float x) {
    return 1.0f / (1.0f + expf(-x));
}

// Wave-reduce 8 values, lane 0 of each wave deposits to LDS.
// NO global atomics anywhere: each block owns ws[bx*8 .. bx*8+7] (64 B line).
__device__ __forceinline__ void commit_wave(double (*sred)[8], int wib, int lane,
                                            float a0, float a1, float a2, float a3,
                                            float a4, float a5, float a6, float a7) {
    float v[8] = {a0, a1, a2, a3, a4, a5, a6, a7};
    #pragma unroll
    for (int s = 0; s < 8; ++s) {
        #pragma unroll
        for (int off = 32; off > 0; off >>= 1)
            v[s] += __shfl_down(v[s], off, 64);
    }
    if (lane == 0) {
        #pragma unroll
        for (int s = 0; s < 8; ++s) sred[wib][s] = (double)v[s];
    }
}

// ws layout (doubles): ws[bx*8 + s], bx in [0,2498), slots:
// 0 sum(cls^2) | 1 sum(cls[...,79]) | 2 sum(conf^2) | 3 noobj_rm
// 4 obj | 5 prior | 6 true | 7 score corr      (total 159,872 B workspace)
__global__ void __launch_bounds__(256)
yolo_fused(const float* __restrict__ cls,
           const float* __restrict__ pred,
           const float* __restrict__ tobj,
           const float* __restrict__ tlab,
           const float* __restrict__ anchors,
           const float* __restrict__ fm_cord,
           const float* __restrict__ fm_size,
           double* __restrict__ ws) {
    const int bx = blockIdx.x;
    const int lane = threadIdx.x & 63;
    const int wib = threadIdx.x >> 6;

    __shared__ double sred[4][8];

    if (bx >= NB_CORR && bx < NB_CORR + NB_CLS) {
        // ---------------- cls: sum(cls^2), sum(cls[...,79]) ----------------
        const int wave = (bx - NB_CORR) * 4 + wib;   // [0, 9028); batch = wave
        float sumsq = 0.0f, sum79 = 0.0f;

        if (wave < CLS_BATCHES) {
            const int b = wave;
            const f32x4* s4 = reinterpret_cast<const f32x4*>(cls) + b * 1024 + lane;
            f32x4 v0  = __builtin_nontemporal_load(s4 + 0 * 64);
            f32x4 v1  = __builtin_nontemporal_load(s4 + 1 * 64);
            f32x4 v2  = __builtin_nontemporal_load(s4 + 2 * 64);
            f32x4 v3  = __builtin_nontemporal_load(s4 + 3 * 64);
            f32x4 v4  = __builtin_nontemporal_load(s4 + 4 * 64);
            f32x4 v5  = __builtin_nontemporal_load(s4 + 5 * 64);
            f32x4 v6  = __builtin_nontemporal_load(s4 + 6 * 64);
            f32x4 v7  = __builtin_nontemporal_load(s4 + 7 * 64);
            f32x4 v8  = __builtin_nontemporal_load(s4 + 8 * 64);
            f32x4 v9  = __builtin_nontemporal_load(s4 + 9 * 64);
            f32x4 v10 = __builtin_nontemporal_load(s4 + 10 * 64);
            f32x4 v11 = __builtin_nontemporal_load(s4 + 11 * 64);
            f32x4 v12 = __builtin_nontemporal_load(s4 + 12 * 64);
            f32x4 v13 = __builtin_nontemporal_load(s4 + 13 * 64);
            f32x4 v14 = __builtin_nontemporal_load(s4 + 14 * 64);
            f32x4 v15 = __builtin_nontemporal_load(s4 + 15 * 64);
            // gi = b*1024 + k*64 + lane ; gi%20 = (base20 + 4k) % 20
            const int base20 = (b * 1024 + lane) % 20;
            const f32x4 vv[16] = {v0, v1, v2, v3, v4, v5, v6, v7,
                                  v8, v9, v10, v11, v12, v13, v14, v15};
            #pragma unroll
            for (int k = 0; k < 16; ++k) {
                f32x4 v = vv[k];
                sumsq += v.x * v.x + v.y * v.y + v.z * v.z + v.w * v.w;
                int t = base20 + 4 * k;           // <= 79
                if (t == 19 || t == 39 || t == 59 || t == 79) sum79 += v.w;
            }
        }

        commit_wave(sred, wib, lane, sumsq, sum79, 0.f, 0.f, 0.f, 0.f, 0.f, 0.f);
    } else if (bx >= NB_CORR + NB_CLS) {
        // ---------------- pred: sum(sigmoid(conf)^2) ----------------
        const int wave = (bx - NB_CORR - NB_CLS) * 4 + wib;  // [0, 564); batch = wave
        float conf2 = 0.0f;

        {
            const int b = wave;
            const f32x4* s4 = reinterpret_cast<const f32x4*>(pred) + b * 1024 + lane;
            f32x4 v0  = __builtin_nontemporal_load(s4 + 0 * 64);
            f32x4 v1  = __builtin_nontemporal_load(s4 + 1 * 64);
            f32x4 v2  = __builtin_nontemporal_load(s4 + 2 * 64);
            f32x4 v3  = __builtin_nontemporal_load(s4 + 3 * 64);
            f32x4 v4  = __builtin_nontemporal_load(s4 + 4 * 64);
            f32x4 v5  = __builtin_nontemporal_load(s4 + 5 * 64);
            f32x4 v6  = __builtin_nontemporal_load(s4 + 6 * 64);
            f32x4 v7  = __builtin_nontemporal_load(s4 + 7 * 64);
            f32x4 v8  = __builtin_nontemporal_load(s4 + 8 * 64);
            f32x4 v9  = __builtin_nontemporal_load(s4 + 9 * 64);
            f32x4 v10 = __builtin_nontemporal_load(s4 + 10 * 64);
            f32x4 v11 = __builtin_nontemporal_load(s4 + 11 * 64);
            f32x4 v12 = __builtin_nontemporal_load(s4 + 12 * 64);
            f32x4 v13 = __builtin_nontemporal_load(s4 + 13 * 64);
            f32x4 v14 = __builtin_nontemporal_load(s4 + 14 * 64);
            f32x4 v15 = __builtin_nontemporal_load(s4 + 15 * 64);
            // gi%5 ; conf component kk = (gi+4)%5 if <4
            const int base5 = (b * 1024 + lane) % 5;
            const f32x4 vv[16] = {v0, v1, v2, v3, v4, v5, v6, v7,
                                  v8, v9, v10, v11, v12, v13, v14, v15};
            #pragma unroll
            for (int k = 0; k < 16; ++k) {
                f32x4 v = vv[k];
                int g5 = (base5 + 4 * k) % 5;
                int kk = (g5 + 4) % 5;            // 4 => no conf element here
                if (kk < 4) {
                    float x = (kk == 0) ? v.x : (kk == 1) ? v.y
                            : (kk == 2) ? v.z : v.w;
                    float c = sigmoidf_(x);
                    conf2 += c * c;
                }
            }
        }

        // tail: 64 float4 (gi = 577536 + lane), last wave only
        if (wave == PRED_BATCHES - 1) {
            int gi = PRED_BATCHES * 1024 + lane;
            float4 v = reinterpret_cast<const float4*>(pred)[gi];
            int kk = (gi + 4) % 5;
            if (kk < 4) {
                float x = (kk == 0) ? v.x : (kk == 1) ? v.y : (kk == 2) ? v.z : v.w;
                float c = sigmoidf_(x);
                conf2 += c * c;
            }
        }

        commit_wave(sred, wib, lane, 0.f, 0.f, conf2, 0.f, 0.f, 0.f, 0.f, 0.f);
    } else {
        // ---------------- sparse corrections (blocks 0..99) ----------------
        const int id = bx * 256 + threadIdx.x;
        float noobj_rm = 0.0f, objs = 0.0f, priors = 0.0f, trues = 0.0f, scorr = 0.0f;

        if (id < BB * TD * AD) {
            int b = id / (TD * AD);
            int r = id % (TD * AD);
            int t = r / AD;
            int a = r % AD;

            const float4 to4 = reinterpret_cast<const float4*>(tobj)[b * TD + t];
            float tox = to4.x * (1.0f / 32.0f);
            float toy = to4.y * (1.0f / 32.0f);
            float tw  = to4.z * (1.0f / 32.0f);
            float th  = to4.w * (1.0f / 32.0f);
            int ii = (int)floorf(tox);
            int jj = (int)floorf(toy);

            const int cell = (b * WD + ii) * HD + jj;
            const float* p = pred + (cell * AD + a) * 5;
            const int fm = (ii * HD + jj) * 2;
            float px = sigmoidf_(p[0]) + fm_cord[fm + 0];
            float py = sigmoidf_(p[1]) + fm_cord[fm + 1];
            float pw = sigmoidf_(p[2]) * fm_size[fm + 0];
            float ph = sigmoidf_(p[3]) * fm_size[fm + 1];
            float conf = sigmoidf_(p[4]);

            float inter = fminf(pw, tw) * fminf(ph, th);
            float uni = pw * ph + tw * th - inter;
            float iou = inter / uni;

            if (iou > 0.5f) {
                noobj_rm = conf * conf;
                objs = (conf - iou) * (conf - iou);
                float aw = anchors[a * 2 + 0];
                float ah = anchors[a * 2 + 1];
                priors = (pw - aw) * (pw - aw) + (ph - ah) * (ph - ah);
                trues = (px - tox) * (px - tox) + (py - toy) * (py - toy)
                      + (pw - tw) * (pw - tw) + (ph - th) * (ph - th);
                // score replacement: sum(cls-tl)^2 - sum(cls-onehot79)^2
                //                  = 2*cls[79] - 2*dot(cls, tl)   (tl one-hot)
                const float4* cl4 = reinterpret_cast<const float4*>(cls + (cell * AD + a) * CD);
                const float4* tl4 = reinterpret_cast<const float4*>(tlab + (b * TD + t) * CD);
                float dot = 0.0f;
                float cl79 = 0.0f;
                #pragma unroll 5
                for (int c = 0; c < CD / 4; ++c) {
                    float4 x = cl4[c];
                    float4 y = tl4[c];
                    dot += x.x * y.x + x.y * y.y + x.z * y.z + x.w * y.w;
                    if (c == CD / 4 - 1) cl79 = x.w;
                }
                scorr = 2.0f * cl79 - 2.0f * dot;
            }
        }

        commit_wave(sred, wib, lane, 0.f, 0.f, 0.f, noobj_rm, objs, priors, trues, scorr);
    }

    __syncthreads();
    if (threadIdx.x < 8) {
        ws[bx * 8 + threadIdx.x] = sred[0][threadIdx.x] + sred[1][threadIdx.x]
                                 + sred[2][threadIdx.x] + sred[3][threadIdx.x];
    }
}

__global__ void __launch_bounds__(1024)
yolo_finalize(const double* __restrict__ ws,
              const int* __restrict__ epoch_p,
              float* __restrict__ out) {
    const int lane = threadIdx.x & 63;
    const int wib = threadIdx.x >> 6;          // 0..15
    __shared__ double sh[16][8];

    double acc[8] = {0.0, 0.0, 0.0, 0.0, 0.0, 0.0, 0.0, 0.0};
    for (int b = threadIdx.x; b < NBLK; b += 1024) {
        #pragma unroll
        for (int s = 0; s < 8; ++s) acc[s] += ws[b * 8 + s];
    }
    #pragma unroll
    for (int s = 0; s < 8; ++s) {
        #pragma unroll
        for (int off = 32; off > 0; off >>= 1)
            acc[s] += __shfl_down(acc[s], off, 64);
    }
    if (lane == 0) {
        #pragma unroll
        for (int s = 0; s < 8; ++s) sh[wib][s] = acc[s];
    }
    __syncthreads();

    if (threadIdx.x == 0) {
        double v[8];
        #pragma unroll
        for (int s = 0; s < 8; ++s) {
            double t = 0.0;
            #pragma unroll
            for (int w = 0; w < 16; ++w) t += sh[w][s];
            v[s] = t;
        }

        const double n1 = (double)N1;
        double sumsq = v[0], sum79 = v[1], conf2 = v[2];
        double rm = v[3], objs = v[4], priors = v[5], trues = v[6], scorr = v[7];

        int ev = epoch_p[0];
        double epoch;
        if (ev >= 0 && ev <= 1000000) {
            epoch = (double)ev;
        } else {
            float f = __int_as_float(ev);
            epoch = (double)f;
        }
        double need_prior = (epoch < 10.0) ? 1.0 : 0.0;

        double noobj_loss = 0.25 * (conf2 - rm) / n1;
        double obj_loss   = 2.5 * objs / n1;
        double prior_loss = need_prior * 2.5 * priors / (2.0 * n1);
        double true_loss  = 2.5 * trues / (4.0 * n1);
        double score_base = sumsq + n1 - 2.0 * sum79;
        double score_loss = 2.5 * (score_base + scorr) / (80.0 * n1);

        out[0] = (float)((noobj_loss + obj_loss + prior_loss + true_loss + score_loss) / 4.0);
    }
}

extern "C" void kernel_launch(void* const* d_in, const int* in_sizes, int n_in,
                              void* d_out, int out_size, void* d_ws, size_t ws_size,
                              hipStream_t stream) {
    const int*   epoch   = (const int*)d_in[0];
    const float* cls     = (const float*)d_in[1];
    const float* pred    = (const float*)d_in[2];
    const float* tobj    = (const float*)d_in[3];
    const float* tlab    = (const float*)d_in[4];
    const float* anchors = (const float*)d_in[5];
    const float* fm_cord = (const float*)d_in[6];
    const float* fm_size = (const float*)d_in[7];
    double* ws = (double*)d_ws;
    float* out = (float*)d_out;

    // No memset needed: every block writes all 8 of its private ws slots.
    yolo_fused<<<NBLK, 256, 0, stream>>>(
        cls, pred, tobj, tlab, anchors, fm_cord, fm_size, ws);

    yolo_finalize<<<1, 1024, 0, stream>>>(ws, epoch, out);
}